// Round 8
// baseline (983.694 us; speedup 1.0000x reference)
//
#include <hip/hip_runtime.h>
#include <hip/hip_bf16.h>

typedef __bf16 bf16x8 __attribute__((ext_vector_type(8)));
typedef __bf16 bf16x4 __attribute__((ext_vector_type(4)));
typedef float  f32x4  __attribute__((ext_vector_type(4)));
typedef float  f32x16 __attribute__((ext_vector_type(16)));

#define LAYERS 16
#define DIM 64
#define NHID 256
#define BATCH 32768
#define MTILE 64
#define NBLOCKS (BATCH / MTILE)   // 512

// packed weight sizes in bf16 elements — SAME sizes, NEW fragment order:
// per (net,layer,gemm): [ot32][kt16][lane(64)][8] with n = ot*32 + (lane&31),
// k = kt*16 + (lane>>5)*8 + j  (A-fragment order for mfma_f32_32x32x16_bf16)
#define W0P_PER 16384             // 8 ot * 4 kt * 512
#define W1P_PER 65536             // 8 ot * 16 kt * 512
#define W2P_PER 16384             // 2 ot * 16 kt * 512
#define W0P_TOT (32 * W0P_PER)    // 524288
#define W1P_TOT (32 * W1P_PER)    // 2097152
#define W2P_TOT (32 * W2P_PER)    // 524288
#define PACK_TOT (W0P_TOT + W1P_TOT + W2P_TOT)  // 3145728 bf16 = 6.29 MB

__device__ __forceinline__ bf16x8 ldw(const __bf16* p) { return *(const bf16x8*)p; }

// ---------------------------------------------------------------------------
// Pack kernel, round 15: analytic masks (unchanged), 32x32-A fragment order.
// ---------------------------------------------------------------------------
__global__ __launch_bounds__(256) void pack_weights(
    const float* __restrict__ lW0, const float* __restrict__ lW1, const float* __restrict__ lW2,
    const float* __restrict__ sW0, const float* __restrict__ sW1, const float* __restrict__ sW2,
    __bf16* __restrict__ ws)
{
    const long i = ((long)blockIdx.x * 256 + threadIdx.x) * 8;  // elem base
    const float* W; long src; int l, n, k, which;
    if (i < W0P_TOT) {
        int netl = (int)(i / W0P_PER), rem = (int)(i % W0P_PER);
        int net = netl >> 4; l = netl & 15;
        int g = rem >> 3, lane = g & 63, kt = (g >> 6) & 3, ot = g >> 8;  // ot 0..7
        n = ot * 32 + (lane & 31); k = kt * 16 + (lane >> 5) * 8;
        W = net ? sW0 : lW0; which = 0;
        src = (long)(l * 256 + n) * 64 + k;
    } else if (i < W0P_TOT + W1P_TOT) {
        long r = i - W0P_TOT;
        int netl = (int)(r / W1P_PER), rem = (int)(r % W1P_PER);
        int net = netl >> 4; l = netl & 15;
        int g = rem >> 3, lane = g & 63, kt = (g >> 6) & 15, ot = g >> 10; // ot 0..7
        n = ot * 32 + (lane & 31); k = kt * 16 + (lane >> 5) * 8;
        W = net ? sW1 : lW1; which = 1;
        src = (long)(l * 256 + n) * 256 + k;
    } else {
        long r = i - W0P_TOT - W1P_TOT;
        int netl = (int)(r / W2P_PER), rem = (int)(r % W2P_PER);
        int net = netl >> 4; l = netl & 15;
        int g = rem >> 3, lane = g & 63, kt = (g >> 6) & 15, ot = g >> 10; // ot 0..1
        n = ot * 32 + (lane & 31); k = kt * 16 + (lane >> 5) * 8;
        W = net ? sW2 : lW2; which = 2;
        src = (long)(l * 64 + n) * 256 + k;
    }
    f32x4 wa = *(const f32x4*)(W + src);
    f32x4 wb = *(const f32x4*)(W + src + 4);
    const int nm = n % 63;                   // mh(n) for which 0/1
    const int pn = (l & 1) ? 63 - n : n;     // perm(n) for which 2 (n < 64 there)
    bf16x8 o;
    #pragma unroll
    for (int j = 0; j < 8; ++j) {
        int kk = k + j;
        bool m;
        if (which == 0)      { int pk = (l & 1) ? 63 - kk : kk; m = (pk <= nm); }
        else if (which == 1) { m = ((kk % 63) <= nm); }
        else                 { m = ((kk % 63) < pn); }
        float v = (j < 4) ? wa[j] : wb[j - 4];
        o[j] = m ? (__bf16)v : (__bf16)0.0f;
    }
    *(bf16x8*)(ws + i) = o;
}

// ---------------------------------------------------------------------------
// Flow kernel, round 15: G1/G2 on mfma_f32_32x32x16_bf16, G3 unchanged
// (16x16x32, r8 mapping). Same 512 thr / 8 waves / 72 KB / 2 blocks/CU
// (waves_per_eu(4), the r12-verified residency knob).
// Why: r8's LDS-read pipe is 61% busy (the top resource). 32x32 MFMA gets
// 32768 FLOP per activation ds_read_b128 at reuse-2 (2x the 16x16 rate),
// halving G2's read stream (256->128 per block-net), and the 32x32 pipe is
// ~14% more cycle-efficient (2382 vs 2075 TF ubench). Same register shape:
// acc 2x16, A-frags 4 regs per 32-row x K16.
// Activation LDS format (all bufs): [bt32][kt16][lane(64)][8], element
// (batch b, k): lane = (b&31) + 32*((k&15)>>3), j = k&7 — B-fragment order
// for 32x32 MFMA; G3's 16x16 reads use a remapped lane (derived inline).
// W1 A-slice = 16kt x 2ot = 128 regs > budget: 8-deep RING — kt0..7
// prefetched across B2 (64 regs), slot kt reloaded with kt+8 right after
// last use (7-iter runway ≈ 112 issue-cyc x 4-wave TLP > L2 ~200cyc; unlike
// r10's zero-runway inline loads).
// ---------------------------------------------------------------------------
__global__ void __attribute__((amdgpu_flat_work_group_size(512, 512)))
                __attribute__((amdgpu_waves_per_eu(4)))
flow_kernel(
    const float* __restrict__ u,
    const __bf16* __restrict__ wp,
    const float* __restrict__ lb0, const float* __restrict__ lb1, const float* __restrict__ lb2,
    const float* __restrict__ sb0, const float* __restrict__ sb1, const float* __restrict__ sb2,
    float* __restrict__ out)
{
    __shared__ __bf16 ybf[2 * 4 * 512];     // [bt32][kt16(4)][lane][8]   8 KB
    __shared__ __bf16 buf1[2 * 16 * 512];   // [bt32][kt16(16)][lane][8] 32 KB
    __shared__ __bf16 buf2[2 * 16 * 512];   //                           32 KB

    const int tid  = threadIdx.x;
    const int w    = tid >> 6;        // 0..7
    const int lane = tid & 63;
    const int quad = lane >> 4;       // 0..3
    const int l16  = lane & 15;
    const int l32  = lane & 31;
    const int hi   = lane >> 5;       // 0..1 (== quad>>1)
    const int q1   = quad & 1;
    const int qp   = q1 * 4;
    const int blk  = blockIdx.x;

    // G1: wave owns ot-tile w (32 hidden rows), both bt32.
    // G2: og = w>>1 -> ot {2og, 2og+1}; bt2 = w&1.
    // G3 (16x16): otD = w>>1 (dim tile), bh = w&1 (batch half) — r8 mapping.
    const int og  = w >> 1;
    const int bt2 = w & 1;
    const int otD = w >> 1;
    const int bh  = w & 1;

    const __bf16* w0p = wp;
    const __bf16* w1p = wp + W0P_TOT;
    const __bf16* w2p = wp + W0P_TOT + W1P_TOT;

    // y regs (r8 layout): y[bt][r] = row (blk*64 + bh*32 + bt*16 + l16),
    //                               dim (otD*16 + quad*4 + r)
    f32x4 y[2];
    #pragma unroll
    for (int bt = 0; bt < 2; ++bt)
        y[bt] = *(const f32x4*)(u + (long)(blk * MTILE + bh * 32 + bt * 16 + l16) * DIM
                                  + otD * 16 + quad * 4);

    // prime: G1 A-frags for (net0, layer0): wave's ot = w, kt 0..3
    bf16x8 wg1[4];
    #pragma unroll
    for (int kt = 0; kt < 4; ++kt)
        wg1[kt] = ldw(w0p + (long)((w * 4 + kt) * 64 + lane) * 8);

    for (int l = 0; l < LAYERS; ++l) {
        // stage y -> ybf B-frags: batch b = bh*32+bt*16+l16, dim d = otD*16+quad*4+r
        // -> bt32 = bh, kt16 = otD, lane32 = bt*16+l16+32*hi, j = qp+r
        #pragma unroll
        for (int bt = 0; bt < 2; ++bt) {
            bf16x4 v;
            #pragma unroll
            for (int r = 0; r < 4; ++r) v[r] = (__bf16)y[bt][r];
            *(bf16x4*)&ybf[((bh * 4 + otD) * 64 + bt * 16 + l16 + 32 * hi) * 8 + qp] = v;
        }
        __syncthreads();  // B1: ybf ready

        f32x4 locr[2], scr[2];

        #pragma unroll
        for (int net = 0; net < 2; ++net) {
            const __bf16* w1b = w1p + (long)(net * 16 + l) * W1P_PER;
            const __bf16* w2b = w2p + (long)(net * 16 + l) * W2P_PER;
            // next G1 slot: net0 -> (net1, l); net1 -> (net0, l+1). l=15/net1
            // lands on slot 16: in-bounds, values unused.
            const __bf16* w0n = w0p + (long)(net == 0 ? 16 + l : l + 1) * W0P_PER;
            const float* b0 = (net ? sb0 : lb0) + l * 256;
            const float* b1 = (net ? sb1 : lb1) + l * 256;
            const float* b2 = (net ? sb2 : lb2) + l * 64;

            bf16x8 wg2a[16];  // G2 A ring: [slot(8)][oi(2)], 64 VGPR

            // ---- G1: W0 (32x32 A, prefetched) x y^T (B frags) -> h0
            {
                f32x16 acc1[2];
                #pragma unroll
                for (int bt = 0; bt < 2; ++bt)
                    #pragma unroll
                    for (int r = 0; r < 16; ++r) acc1[bt][r] = 0.f;
                #pragma unroll
                for (int kt = 0; kt < 4; ++kt) {
                    bf16x8 bv[2];
                    #pragma unroll
                    for (int bt = 0; bt < 2; ++bt)
                        bv[bt] = *(const bf16x8*)&ybf[((bt * 4 + kt) * 64 + lane) * 8];
                    #pragma unroll
                    for (int bt = 0; bt < 2; ++bt)
                        acc1[bt] = __builtin_amdgcn_mfma_f32_32x32x16_bf16(wg1[kt], bv[bt], acc1[bt], 0, 0, 0);
                }
                // prefetch G2 ring slots kt=0..7 across the upcoming barrier
                #pragma unroll
                for (int kt = 0; kt < 8; ++kt)
                    #pragma unroll
                    for (int oi = 0; oi < 2; ++oi)
                        wg2a[kt * 2 + oi] = ldw(w1b + (long)(((2 * og + oi) * 16 + kt) * 64 + lane) * 8);
                // epilogue: relu+bias -> buf1 frags. D: col=l32 (batch within bt),
                // row = (r&3)+8*(r>>2)+4*hi. Quad-group q (regs 4q..4q+3):
                // H = w*32+8q+4hi+r -> kt16 = w*2+(q>>1), lane32 = l32+32*(q&1),
                // j = 4hi+r. One bf16x4 write per (bt,q).
                #pragma unroll
                for (int bt = 0; bt < 2; ++bt)
                    #pragma unroll
                    for (int q = 0; q < 4; ++q) {
                        f32x4 bias = *(const f32x4*)(b0 + w * 32 + 8 * q + 4 * hi);
                        bf16x4 v;
                        #pragma unroll
                        for (int r = 0; r < 4; ++r)
                            v[r] = (__bf16)fmaxf(acc1[bt][4 * q + r] + bias[r], 0.f);
                        *(bf16x4*)&buf1[((bt * 16 + w * 2 + (q >> 1)) * 64
                                         + l32 + 32 * (q & 1)) * 8 + 4 * hi] = v;
                    }
            }
            __syncthreads();  // B2: h0 ready

            bf16x8 wg3[8];    // G3 A (16x16) from 32x32-packed W2

            // ---- G2: W1 (32x32 A, 8-deep ring) x h0 -> h1
            {
                f32x16 acc2[2];
                #pragma unroll
                for (int oi = 0; oi < 2; ++oi)
                    #pragma unroll
                    for (int r = 0; r < 16; ++r) acc2[oi][r] = 0.f;
                #pragma unroll
                for (int kt = 0; kt < 16; ++kt) {
                    const int slot = kt & 7;
                    bf16x8 bv = *(const bf16x8*)&buf1[((bt2 * 16 + kt) * 64 + lane) * 8];
                    #pragma unroll
                    for (int oi = 0; oi < 2; ++oi)
                        acc2[oi] = __builtin_amdgcn_mfma_f32_32x32x16_bf16(wg2a[slot * 2 + oi], bv, acc2[oi], 0, 0, 0);
                    if (kt < 8) {
                        #pragma unroll
                        for (int oi = 0; oi < 2; ++oi)
                            wg2a[slot * 2 + oi] = ldw(w1b + (long)(((2 * og + oi) * 16 + kt + 8) * 64 + lane) * 8);
                    }
                }
                // G3 A-prefetch (overlaps epilogue + barrier): 16x16 frag
                // (n = otD*16+l16, k = kt32*32+quad*8) from packed-32 W2:
                // ot32 = otD>>1, kt16 = kt32*2+hi, lane_p = (otD&1)*16+l16+32*q1
                #pragma unroll
                for (int kt = 0; kt < 8; ++kt)
                    wg3[kt] = ldw(w2b + (long)((((otD >> 1) * 16 + kt * 2 + hi) * 64
                                               + (otD & 1) * 16 + l16 + 32 * q1) * 8));
                // epilogue: relu+bias -> buf2 frags (same mapping, ot = 2og+oi)
                #pragma unroll
                for (int oi = 0; oi < 2; ++oi) {
                    const int ot = 2 * og + oi;
                    #pragma unroll
                    for (int q = 0; q < 4; ++q) {
                        f32x4 bias = *(const f32x4*)(b1 + ot * 32 + 8 * q + 4 * hi);
                        bf16x4 v;
                        #pragma unroll
                        for (int r = 0; r < 4; ++r)
                            v[r] = (__bf16)fmaxf(acc2[oi][4 * q + r] + bias[r], 0.f);
                        *(bf16x4*)&buf2[((bt2 * 16 + ot * 2 + (q >> 1)) * 64
                                         + l32 + 32 * (q & 1)) * 8 + 4 * hi] = v;
                    }
                }
            }
            __syncthreads();  // B3: h1 ready (all buf1 reads done)

            // ---- G3: W2 (16x16 A, prefetched in wg3) x h1 -> regs (r8 mapping)
            // wave owns (dim tile otD, batch half bh): bt16 in {2bh, 2bh+1}
            {
                f32x4 acc3[2];
                #pragma unroll
                for (int bt = 0; bt < 2; ++bt)
                    acc3[bt] = (f32x4){0.f, 0.f, 0.f, 0.f};
                #pragma unroll
                for (int kt = 0; kt < 8; ++kt) {      // kt32 over K=256
                    #pragma unroll
                    for (int bt = 0; bt < 2; ++bt) {
                        // B-frag 16x16x32: col = (2bh+bt)*16+l16, k = kt*32+quad*8
                        // from act format: bt32 = bh, kt16 = kt*2+hi,
                        // lane32 = bt*16+l16+32*q1
                        bf16x8 bv = *(const bf16x8*)&buf2[((bh * 16 + kt * 2 + hi) * 64
                                                           + bt * 16 + l16 + 32 * q1) * 8];
                        acc3[bt] = __builtin_amdgcn_mfma_f32_16x16x32_bf16(wg3[kt], bv, acc3[bt], 0, 0, 0);
                    }
                }
                // prefetch next G1 A-frags (low-pressure region)
                #pragma unroll
                for (int kt = 0; kt < 4; ++kt)
                    wg1[kt] = ldw(w0n + (long)((w * 4 + kt) * 64 + lane) * 8);
                f32x4 bias = *(const f32x4*)(b2 + otD * 16 + quad * 4);
                if (net == 0) {
                    #pragma unroll
                    for (int bt = 0; bt < 2; ++bt)
                        #pragma unroll
                        for (int r = 0; r < 4; ++r)
                            locr[bt][r] = acc3[bt][r] + bias[r];
                } else {
                    #pragma unroll
                    for (int bt = 0; bt < 2; ++bt)
                        #pragma unroll
                        for (int r = 0; r < 4; ++r)
                            scr[bt][r] = acc3[bt][r] + bias[r];
                }
            }
            // no barrier after G3: next G1 writes buf1 (reads drained at B3);
            // next G2's buf2 writes are behind the next B2
        }

        // coupling update, pure registers: y = exp(-sc) * (y - loc)
        #pragma unroll
        for (int bt = 0; bt < 2; ++bt)
            #pragma unroll
            for (int r = 0; r < 4; ++r)
                y[bt][r] = __expf(-scr[bt][r]) * (y[bt][r] - locr[bt][r]);
        // next ybf write safe: all ybf readers (both nets' G1) are behind this
        // layer's B2 barriers
    }

    #pragma unroll
    for (int bt = 0; bt < 2; ++bt)
        *(f32x4*)(out + (long)(blk * MTILE + bh * 32 + bt * 16 + l16) * DIM
                      + otD * 16 + quad * 4) = y[bt];
}

extern "C" void kernel_launch(void* const* d_in, const int* in_sizes, int n_in,
                              void* d_out, int out_size, void* d_ws, size_t ws_size,
                              hipStream_t stream) {
    const float* u   = (const float*)d_in[0];
    const float* lW0 = (const float*)d_in[1];
    const float* lb0 = (const float*)d_in[2];
    const float* lW1 = (const float*)d_in[3];
    const float* lb1 = (const float*)d_in[4];
    const float* lW2 = (const float*)d_in[5];
    const float* lb2 = (const float*)d_in[6];
    const float* sW0 = (const float*)d_in[7];
    const float* sb0 = (const float*)d_in[8];
    const float* sW1 = (const float*)d_in[9];
    const float* sb1 = (const float*)d_in[10];
    const float* sW2 = (const float*)d_in[11];
    const float* sb2 = (const float*)d_in[12];
    // d_in[13..15] = M0,M1,M2 — masks are computed analytically in pack_weights

    if (ws_size < (size_t)PACK_TOT * sizeof(__bf16)) return;
    __bf16* ws = (__bf16*)d_ws;

    pack_weights<<<PACK_TOT / 8 / 256, 256, 0, stream>>>(
        lW0, lW1, lW2, sW0, sW1, sW2, ws);
    flow_kernel<<<NBLOCKS, 512, 0, stream>>>(
        u, ws, lb0, lb1, lb2, sb0, sb1, sb2, (float*)d_out);
}

// Round 9
// 481.083 us; speedup vs baseline: 2.0447x; 2.0447x over previous
//
#include <hip/hip_runtime.h>
#include <hip/hip_bf16.h>

typedef __bf16 bf16x8 __attribute__((ext_vector_type(8)));
typedef __bf16 bf16x4 __attribute__((ext_vector_type(4)));
typedef float  f32x4  __attribute__((ext_vector_type(4)));

#define LAYERS 16
#define DIM 64
#define NHID 256
#define BATCH 32768
#define MTILE 64
#define NBLOCKS (BATCH / MTILE)   // 512

// packed weight sizes in bf16 elements (r8/r12 16x16 fragment order)
#define W0P_PER 16384             // per (net,layer): 16 otiles * 2 ktiles * 512
#define W1P_PER 65536             // 16 otiles * 8 ktiles * 512
#define W2P_PER 16384             // 4 otiles * 8 ktiles * 512
#define W0P_TOT (32 * W0P_PER)    // 524288
#define W1P_TOT (32 * W1P_PER)    // 2097152
#define W2P_TOT (32 * W2P_PER)    // 524288
#define PACK_TOT (W0P_TOT + W1P_TOT + W2P_TOT)  // 3145728 bf16 = 6.29 MB

__device__ __forceinline__ bf16x8 ldw(const __bf16* p) { return *(const bf16x8*)p; }

// ---------------------------------------------------------------------------
// Pack kernel: REVERTED to the r8/r12 16x16 fragment order (r15's 32x32
// order is dead with the 32x32 design). Analytic masks.
// ---------------------------------------------------------------------------
__global__ __launch_bounds__(256) void pack_weights(
    const float* __restrict__ lW0, const float* __restrict__ lW1, const float* __restrict__ lW2,
    const float* __restrict__ sW0, const float* __restrict__ sW1, const float* __restrict__ sW2,
    __bf16* __restrict__ ws)
{
    const long i = ((long)blockIdx.x * 256 + threadIdx.x) * 8;  // elem base
    const float* W; long src; int l, n, k, which;
    if (i < W0P_TOT) {
        int netl = (int)(i / W0P_PER), rem = (int)(i % W0P_PER);
        int net = netl >> 4; l = netl & 15;
        int nt = rem >> 10, kt = (rem >> 9) & 1, lane = (rem >> 3) & 63;
        n = nt * 16 + (lane & 15); k = kt * 32 + (lane >> 4) * 8;
        W = net ? sW0 : lW0; which = 0;
        src = (long)(l * 256 + n) * 64 + k;
    } else if (i < W0P_TOT + W1P_TOT) {
        long r = i - W0P_TOT;
        int netl = (int)(r / W1P_PER), rem = (int)(r % W1P_PER);
        int net = netl >> 4; l = netl & 15;
        int nt = rem >> 12, kt = (rem >> 9) & 7, lane = (rem >> 3) & 63;
        n = nt * 16 + (lane & 15); k = kt * 32 + (lane >> 4) * 8;
        W = net ? sW1 : lW1; which = 1;
        src = (long)(l * 256 + n) * 256 + k;
    } else {
        long r = i - W0P_TOT - W1P_TOT;
        int netl = (int)(r / W2P_PER), rem = (int)(r % W2P_PER);
        int net = netl >> 4; l = netl & 15;
        int nt = rem >> 12, kt = (rem >> 9) & 7, lane = (rem >> 3) & 63;
        n = nt * 16 + (lane & 15); k = kt * 32 + (lane >> 4) * 8;
        W = net ? sW2 : lW2; which = 2;
        src = (long)(l * 64 + n) * 256 + k;
    }
    f32x4 wa = *(const f32x4*)(W + src);
    f32x4 wb = *(const f32x4*)(W + src + 4);
    const int nm = n % 63;                   // mh(n) for which 0/1
    const int pn = (l & 1) ? 63 - n : n;     // perm(n) for which 2 (n < 64 there)
    bf16x8 o;
    #pragma unroll
    for (int j = 0; j < 8; ++j) {
        int kk = k + j;
        bool m;
        if (which == 0)      { int pk = (l & 1) ? 63 - kk : kk; m = (pk <= nm); }
        else if (which == 1) { m = ((kk % 63) <= nm); }
        else                 { m = ((kk % 63) < pn); }
        float v = (j < 4) ? wa[j] : wb[j - 4];
        o[j] = m ? (__bf16)v : (__bf16)0.0f;
    }
    *(bf16x8*)(ws + i) = o;
}

// ---------------------------------------------------------------------------
// Flow kernel, round 16: r12 champion (234us: 512thr/8 waves/72KB/
// waves_per_eu(4) -> 2 blocks/CU) with ONE change: G2 goes reuse-4 with a
// RING-4 weight prefetch.
//   Why: LDS-read pipe is the top resource (448 ds_read_b128/block-net
//   ~61% of cycles); G2 is 256 of them. Reuse-4 (wave owns 4 otiles x
//   2 batch-tiles, r9's correctness-proven G2 split) halves G2 reads
//   (256->128; total 448->320, -29%).
//   Why it fits now (unlike r9/r15): ring-4 keeps weight regs at 64
//   (wg2a[16 frags]: kt0..3 prefetched across B2; slot kt&3 reloaded with
//   kt+4 AFTER its MFMAs -> 3-iteration runway ~120 issue-cyc x 4-wave TLP
//   > L2 ~200cyc, unlike r10's zero-runway inline loads). Worst-point live
//   set ~125 <= 128-total-reg cap (waves_per_eu(4), r12-verified knob).
// G1 (reuse-2), G3, staging, barriers: byte-identical to r12.
// ---------------------------------------------------------------------------
__global__ void __attribute__((amdgpu_flat_work_group_size(512, 512)))
                __attribute__((amdgpu_waves_per_eu(4)))
flow_kernel(
    const float* __restrict__ u,
    const __bf16* __restrict__ wp,
    const float* __restrict__ lb0, const float* __restrict__ lb1, const float* __restrict__ lb2,
    const float* __restrict__ sb0, const float* __restrict__ sb1, const float* __restrict__ sb2,
    float* __restrict__ out)
{
    __shared__ __bf16 ybf[4 * 2 * 512];     // [bt][kt(2)][lane][8]   8 KB
    __shared__ __bf16 buf1[4 * 8 * 512];    // [bt][kt(8)][lane][8]  32 KB
    __shared__ __bf16 buf2[4 * 8 * 512];    //                       32 KB

    const int tid  = threadIdx.x;
    const int w    = tid >> 6;        // 0..7
    const int lane = tid & 63;
    const int quad = lane >> 4;
    const int l16  = lane & 15;
    const int blk  = blockIdx.x;

    const int qh = quad >> 1;
    const int qp = (quad & 1) * 4;

    const int og  = w >> 1;           // G2 otile group {4og..4og+3}; G3 dim tile
    const int bh  = w & 1;            // G2/G3 batch half: bt {2bh, 2bh+1}

    const __bf16* w0p = wp;
    const __bf16* w1p = wp + W0P_TOT;
    const __bf16* w2p = wp + W0P_TOT + W1P_TOT;

    // y regs: y[bt][r] = row (blk*64 + bh*32 + bt*16 + l16), dim (og*16 + quad*4 + r)
    f32x4 y[2];
    #pragma unroll
    for (int bt = 0; bt < 2; ++bt)
        y[bt] = *(const f32x4*)(u + (long)(blk * MTILE + bh * 32 + bt * 16 + l16) * DIM
                                  + og * 16 + quad * 4);

    // y-staging fragment coords (r12): ktY = w>>2, flY as derived there
    const int ktY = w >> 2;
    const int flY = ((((w >> 1) & 1) * 2 + qh) * 16 + l16);

    // prime: G1 weights for (net0, layer0) — wave's G1 otiles are {2w, 2w+1}
    bf16x8 wg1[4];   // [oi][kt]
    #pragma unroll
    for (int oi = 0; oi < 2; ++oi)
        #pragma unroll
        for (int kt = 0; kt < 2; ++kt)
            wg1[oi * 2 + kt] = ldw(w0p + (long)((2 * w + oi) * 2 + kt) * 512 + lane * 8);

    for (int l = 0; l < LAYERS; ++l) {
        // stage y -> bf16 B-fragments (one b64 write per bt)
        #pragma unroll
        for (int bt = 0; bt < 2; ++bt) {
            bf16x4 v;
            #pragma unroll
            for (int r = 0; r < 4; ++r) v[r] = (__bf16)y[bt][r];
            *(bf16x4*)&ybf[(((bh * 2 + bt) * 2 + ktY) * 64 + flY) * 8 + qp] = v;
        }
        __syncthreads();  // B1: ybf ready

        f32x4 locr[2], scr[2];

        #pragma unroll
        for (int net = 0; net < 2; ++net) {
            const __bf16* w1b = w1p + (long)(net * 16 + l) * W1P_PER;
            const __bf16* w2b = w2p + (long)(net * 16 + l) * W2P_PER;
            // next G1 slot: net0 -> (net1, l); net1 -> (net0, l+1). l=15/net1
            // lands on slot 16 (net1, l0): in-bounds, values unused.
            const __bf16* w0n = w0p + (long)(net == 0 ? 16 + l : l + 1) * W0P_PER;
            const float* b0 = (net ? sb0 : lb0) + l * 256;
            const float* b1 = (net ? sb1 : lb1) + l * 256;
            const float* b2 = (net ? sb2 : lb2) + l * 64;

            bf16x8 wg2a[16];  // G2 A ring: [slot(4)][oi(4)], 64 VGPR

            // ---- G1: W0 (A, prefetched in wg1) x y^T (B, fragments) -> h0 frags
            // (r12 reuse-2: wave owns otiles {2w,2w+1}, all 4 bt)
            {
                f32x4 acc[2][4];
                #pragma unroll
                for (int oi = 0; oi < 2; ++oi)
                    #pragma unroll
                    for (int bt = 0; bt < 4; ++bt)
                        acc[oi][bt] = (f32x4){0.f, 0.f, 0.f, 0.f};
                #pragma unroll
                for (int kt = 0; kt < 2; ++kt) {
                    bf16x8 bv[4];
                    #pragma unroll
                    for (int bt = 0; bt < 4; ++bt)
                        bv[bt] = *(const bf16x8*)&ybf[((bt * 2 + kt) * 64 + lane) * 8];
                    #pragma unroll
                    for (int oi = 0; oi < 2; ++oi)
                        #pragma unroll
                        for (int bt = 0; bt < 4; ++bt)
                            acc[oi][bt] = __builtin_amdgcn_mfma_f32_16x16x32_bf16(wg1[oi * 2 + kt], bv[bt], acc[oi][bt], 0, 0, 0);
                }
                // prefetch G2 ring slots kt=0..3 (otiles {4og..4og+3}) across B2
                #pragma unroll
                for (int kt = 0; kt < 4; ++kt)
                    #pragma unroll
                    for (int oi = 0; oi < 4; ++oi)
                        wg2a[kt * 4 + oi] = ldw(w1b + (long)((4 * og + oi) * 8 + kt) * 512 + lane * 8);
                // epilogue: relu + bias -> buf1 fragments (kt1 = w)
                #pragma unroll
                for (int oi = 0; oi < 2; ++oi) {
                    f32x4 bias = *(const f32x4*)(b0 + (2 * w + oi) * 16 + quad * 4);
                    const int fl = ((oi * 2 + qh) * 16 + l16);
                    #pragma unroll
                    for (int bt = 0; bt < 4; ++bt) {
                        bf16x4 v;
                        #pragma unroll
                        for (int r = 0; r < 4; ++r)
                            v[r] = (__bf16)fmaxf(acc[oi][bt][r] + bias[r], 0.f);
                        *(bf16x4*)&buf1[((bt * 8 + w) * 64 + fl) * 8 + qp] = v;
                    }
                }
            }
            __syncthreads();  // B2: h0 ready

            bf16x8 wg3[8];    // G3 weights [kt]

            // ---- G2: W1 (A, ring-4) x h0 (B, fragments) -> h1 frags
            // REUSE-4: wave owns otiles {4og..4og+3}, batch tiles {2bh,2bh+1}.
            // Each bv read feeds 4 MFMAs; 16 reads/wave (was 32).
            {
                f32x4 acc[4][2];
                #pragma unroll
                for (int oi = 0; oi < 4; ++oi)
                    #pragma unroll
                    for (int bl = 0; bl < 2; ++bl)
                        acc[oi][bl] = (f32x4){0.f, 0.f, 0.f, 0.f};
                #pragma unroll
                for (int kt = 0; kt < 8; ++kt) {
                    const int slot = kt & 3;
                    bf16x8 bv[2];
                    #pragma unroll
                    for (int bl = 0; bl < 2; ++bl)
                        bv[bl] = *(const bf16x8*)&buf1[(((2 * bh + bl) * 8 + kt) * 64 + lane) * 8];
                    #pragma unroll
                    for (int oi = 0; oi < 4; ++oi)
                        #pragma unroll
                        for (int bl = 0; bl < 2; ++bl)
                            acc[oi][bl] = __builtin_amdgcn_mfma_f32_16x16x32_bf16(wg2a[slot * 4 + oi], bv[bl], acc[oi][bl], 0, 0, 0);
                    // ring reload: slot just consumed gets kt+4 (3-iter runway)
                    if (kt < 4) {
                        #pragma unroll
                        for (int oi = 0; oi < 4; ++oi)
                            wg2a[slot * 4 + oi] = ldw(w1b + (long)((4 * og + oi) * 8 + (kt + 4)) * 512 + lane * 8);
                    }
                }
                // epilogue: relu + bias -> buf2 fragments (r9's proven mapping)
                #pragma unroll
                for (int oi = 0; oi < 4; ++oi) {
                    const int O = 4 * og + oi;
                    f32x4 bias = *(const f32x4*)(b1 + O * 16 + quad * 4);
                    const int kt1 = O >> 1;
                    const int fl  = ((O & 1) * 2 + qh) * 16 + l16;
                    #pragma unroll
                    for (int bl = 0; bl < 2; ++bl) {
                        bf16x4 v;
                        #pragma unroll
                        for (int r = 0; r < 4; ++r)
                            v[r] = (__bf16)fmaxf(acc[oi][bl][r] + bias[r], 0.f);
                        *(bf16x4*)&buf2[(((2 * bh + bl) * 8 + kt1) * 64 + fl) * 8 + qp] = v;
                    }
                }
                // prefetch G3 weights across the upcoming barrier
                #pragma unroll
                for (int kt = 0; kt < 8; ++kt)
                    wg3[kt] = ldw(w2b + (long)(og * 8 + kt) * 512 + lane * 8);
            }
            __syncthreads();  // B3: h1 ready (also all buf1 reads done)

            // ---- G3: W2 (A, prefetched in wg3) x h1 (B, fragments) -> regs
            // wave owns (dim tile og, batch half bh): bt in {2bh, 2bh+1}
            {
                f32x4 acc3[2];
                #pragma unroll
                for (int bt = 0; bt < 2; ++bt)
                    acc3[bt] = (f32x4){0.f, 0.f, 0.f, 0.f};
                #pragma unroll
                for (int kt = 0; kt < 8; ++kt) {
                    #pragma unroll
                    for (int bt = 0; bt < 2; ++bt) {
                        bf16x8 bv = *(const bf16x8*)&buf2[(((bh * 2 + bt) * 8 + kt) * 64 + lane) * 8];
                        acc3[bt] = __builtin_amdgcn_mfma_f32_16x16x32_bf16(wg3[kt], bv, acc3[bt], 0, 0, 0);
                    }
                }
                // prefetch next G1 weights (low-pressure region)
                #pragma unroll
                for (int oi = 0; oi < 2; ++oi)
                    #pragma unroll
                    for (int kt = 0; kt < 2; ++kt)
                        wg1[oi * 2 + kt] = ldw(w0n + (long)((2 * w + oi) * 2 + kt) * 512 + lane * 8);
                f32x4 bias = *(const f32x4*)(b2 + og * 16 + quad * 4);
                if (net == 0) {
                    #pragma unroll
                    for (int bt = 0; bt < 2; ++bt)
                        #pragma unroll
                        for (int r = 0; r < 4; ++r)
                            locr[bt][r] = acc3[bt][r] + bias[r];
                } else {
                    #pragma unroll
                    for (int bt = 0; bt < 2; ++bt)
                        #pragma unroll
                        for (int r = 0; r < 4; ++r)
                            scr[bt][r] = acc3[bt][r] + bias[r];
                }
            }
            // no barrier after G3: next G1 writes buf1 (reads drained at B3);
            // next G2's buf2 writes are behind the next B2
        }

        // coupling update, pure registers: y = exp(-sc) * (y - loc)
        #pragma unroll
        for (int bt = 0; bt < 2; ++bt)
            #pragma unroll
            for (int r = 0; r < 4; ++r)
                y[bt][r] = __expf(-scr[bt][r]) * (y[bt][r] - locr[bt][r]);
        // next ybf write safe: all ybf readers (both nets' G1) are behind this
        // layer's B2 barriers
    }

    #pragma unroll
    for (int bt = 0; bt < 2; ++bt)
        *(f32x4*)(out + (long)(blk * MTILE + bh * 32 + bt * 16 + l16) * DIM
                      + og * 16 + quad * 4) = y[bt];
}

extern "C" void kernel_launch(void* const* d_in, const int* in_sizes, int n_in,
                              void* d_out, int out_size, void* d_ws, size_t ws_size,
                              hipStream_t stream) {
    const float* u   = (const float*)d_in[0];
    const float* lW0 = (const float*)d_in[1];
    const float* lb0 = (const float*)d_in[2];
    const float* lW1 = (const float*)d_in[3];
    const float* lb1 = (const float*)d_in[4];
    const float* lW2 = (const float*)d_in[5];
    const float* lb2 = (const float*)d_in[6];
    const float* sW0 = (const float*)d_in[7];
    const float* sb0 = (const float*)d_in[8];
    const float* sW1 = (const float*)d_in[9];
    const float* sb1 = (const float*)d_in[10];
    const float* sW2 = (const float*)d_in[11];
    const float* sb2 = (const float*)d_in[12];
    // d_in[13..15] = M0,M1,M2 — masks are computed analytically in pack_weights

    if (ws_size < (size_t)PACK_TOT * sizeof(__bf16)) return;
    __bf16* ws = (__bf16*)d_ws;

    pack_weights<<<PACK_TOT / 8 / 256, 256, 0, stream>>>(
        lW0, lW1, lW2, sW0, sW1, sW2, ws);
    flow_kernel<<<NBLOCKS, 512, 0, stream>>>(
        u, ws, lb0, lb1, lb2, sb0, sb1, sb2, (float*)d_out);
}

// Round 10
// 419.438 us; speedup vs baseline: 2.3453x; 1.1470x over previous
//
#include <hip/hip_runtime.h>
#include <hip/hip_bf16.h>

typedef __bf16 bf16x8 __attribute__((ext_vector_type(8)));
typedef __bf16 bf16x4 __attribute__((ext_vector_type(4)));
typedef float  f32x4  __attribute__((ext_vector_type(4)));

#define LAYERS 16
#define DIM 64
#define NHID 256
#define BATCH 32768
#define MTILE 64
#define NBLOCKS (BATCH / MTILE)   // 512

// packed weight sizes in bf16 elements (r8/r12 16x16 fragment order)
#define W0P_PER 16384             // per (net,layer): 16 otiles * 2 ktiles * 512
#define W1P_PER 65536             // 16 otiles * 8 ktiles * 512
#define W2P_PER 16384             // 4 otiles * 8 ktiles * 512
#define W0P_TOT (32 * W0P_PER)    // 524288
#define W1P_TOT (32 * W1P_PER)    // 2097152
#define W2P_TOT (32 * W2P_PER)    // 524288
#define PACK_TOT (W0P_TOT + W1P_TOT + W2P_TOT)  // 3145728 bf16 = 6.29 MB

__device__ __forceinline__ bf16x8 ldw(const __bf16* p) { return *(const bf16x8*)p; }

// ---------------------------------------------------------------------------
// Pack kernel (r12, unchanged): analytic masks, 16x16 fragment order.
// ---------------------------------------------------------------------------
__global__ __launch_bounds__(256) void pack_weights(
    const float* __restrict__ lW0, const float* __restrict__ lW1, const float* __restrict__ lW2,
    const float* __restrict__ sW0, const float* __restrict__ sW1, const float* __restrict__ sW2,
    __bf16* __restrict__ ws)
{
    const long i = ((long)blockIdx.x * 256 + threadIdx.x) * 8;  // elem base
    const float* W; long src; int l, n, k, which;
    if (i < W0P_TOT) {
        int netl = (int)(i / W0P_PER), rem = (int)(i % W0P_PER);
        int net = netl >> 4; l = netl & 15;
        int nt = rem >> 10, kt = (rem >> 9) & 1, lane = (rem >> 3) & 63;
        n = nt * 16 + (lane & 15); k = kt * 32 + (lane >> 4) * 8;
        W = net ? sW0 : lW0; which = 0;
        src = (long)(l * 256 + n) * 64 + k;
    } else if (i < W0P_TOT + W1P_TOT) {
        long r = i - W0P_TOT;
        int netl = (int)(r / W1P_PER), rem = (int)(r % W1P_PER);
        int net = netl >> 4; l = netl & 15;
        int nt = rem >> 12, kt = (rem >> 9) & 7, lane = (rem >> 3) & 63;
        n = nt * 16 + (lane & 15); k = kt * 32 + (lane >> 4) * 8;
        W = net ? sW1 : lW1; which = 1;
        src = (long)(l * 256 + n) * 256 + k;
    } else {
        long r = i - W0P_TOT - W1P_TOT;
        int netl = (int)(r / W2P_PER), rem = (int)(r % W2P_PER);
        int net = netl >> 4; l = netl & 15;
        int nt = rem >> 12, kt = (rem >> 9) & 7, lane = (rem >> 3) & 63;
        n = nt * 16 + (lane & 15); k = kt * 32 + (lane >> 4) * 8;
        W = net ? sW2 : lW2; which = 2;
        src = (long)(l * 64 + n) * 256 + k;
    }
    f32x4 wa = *(const f32x4*)(W + src);
    f32x4 wb = *(const f32x4*)(W + src + 4);
    const int nm = n % 63;                   // mh(n) for which 0/1
    const int pn = (l & 1) ? 63 - n : n;     // perm(n) for which 2 (n < 64 there)
    bf16x8 o;
    #pragma unroll
    for (int j = 0; j < 8; ++j) {
        int kk = k + j;
        bool m;
        if (which == 0)      { int pk = (l & 1) ? 63 - kk : kk; m = (pk <= nm); }
        else if (which == 1) { m = ((kk % 63) <= nm); }
        else                 { m = ((kk % 63) < pn); }
        float v = (j < 4) ? wa[j] : wb[j - 4];
        o[j] = m ? (__bf16)v : (__bf16)0.0f;
    }
    *(bf16x8*)(ws + i) = o;
}

// ---------------------------------------------------------------------------
// Flow kernel, round 17: r16 (G2 reuse-4, 4ot x 2bt) with the ring slimmed
// to fit the 128-total-reg budget.
// r16 post-mortem: worst-point live = acc(32) + RING-4(64) + bv[2](8) +
// y(8) + locr(8) + addr(~16) ~= 136 > 128 -> heavy spill (FETCH 317MB).
// Changes vs r16 (both register-diet, nothing else):
//   * ring-4 -> RING-3: wg2a[12 frags] = 48 regs (slots kt%3; kt0..2
//     prefetched across B2; slot reloaded with kt+3 after its MFMAs ->
//     2-iteration runway ~320 CU-cyc at 4-wave TLP > L2 ~200cyc).
//   * bv read one batch-tile at a time (4 regs, not 8).
// Worst-point live ~= 116-120 <= 128 (with the observed ~10-low estimate
// bias). G1/G3/staging/barriers/pack: byte-identical to r12 (proven).
// G2's 4ot x 2bt epilogue mapping: correctness-proven by r16 (passed).
// Effect: G2 B-reads 256 -> 128 per block-net; total 448 -> 320 (-29%);
// LDS read pipe ~61% -> ~44% busy.
// ---------------------------------------------------------------------------
__global__ void __attribute__((amdgpu_flat_work_group_size(512, 512)))
                __attribute__((amdgpu_waves_per_eu(4)))
flow_kernel(
    const float* __restrict__ u,
    const __bf16* __restrict__ wp,
    const float* __restrict__ lb0, const float* __restrict__ lb1, const float* __restrict__ lb2,
    const float* __restrict__ sb0, const float* __restrict__ sb1, const float* __restrict__ sb2,
    float* __restrict__ out)
{
    __shared__ __bf16 ybf[4 * 2 * 512];     // [bt][kt(2)][lane][8]   8 KB
    __shared__ __bf16 buf1[4 * 8 * 512];    // [bt][kt(8)][lane][8]  32 KB
    __shared__ __bf16 buf2[4 * 8 * 512];    //                       32 KB

    const int tid  = threadIdx.x;
    const int w    = tid >> 6;        // 0..7
    const int lane = tid & 63;
    const int quad = lane >> 4;
    const int l16  = lane & 15;
    const int blk  = blockIdx.x;

    const int qh = quad >> 1;
    const int qp = (quad & 1) * 4;

    const int og  = w >> 1;           // G2 otile group {4og..4og+3}; G3 dim tile
    const int bh  = w & 1;            // G2/G3 batch half: bt {2bh, 2bh+1}

    const __bf16* w0p = wp;
    const __bf16* w1p = wp + W0P_TOT;
    const __bf16* w2p = wp + W0P_TOT + W1P_TOT;

    // y regs: y[bt][r] = row (blk*64 + bh*32 + bt*16 + l16), dim (og*16 + quad*4 + r)
    f32x4 y[2];
    #pragma unroll
    for (int bt = 0; bt < 2; ++bt)
        y[bt] = *(const f32x4*)(u + (long)(blk * MTILE + bh * 32 + bt * 16 + l16) * DIM
                                  + og * 16 + quad * 4);

    // y-staging fragment coords (r12)
    const int ktY = w >> 2;
    const int flY = ((((w >> 1) & 1) * 2 + qh) * 16 + l16);

    // prime: G1 weights for (net0, layer0) — wave's G1 otiles are {2w, 2w+1}
    bf16x8 wg1[4];   // [oi][kt]
    #pragma unroll
    for (int oi = 0; oi < 2; ++oi)
        #pragma unroll
        for (int kt = 0; kt < 2; ++kt)
            wg1[oi * 2 + kt] = ldw(w0p + (long)((2 * w + oi) * 2 + kt) * 512 + lane * 8);

    for (int l = 0; l < LAYERS; ++l) {
        // stage y -> bf16 B-fragments (one b64 write per bt)
        #pragma unroll
        for (int bt = 0; bt < 2; ++bt) {
            bf16x4 v;
            #pragma unroll
            for (int r = 0; r < 4; ++r) v[r] = (__bf16)y[bt][r];
            *(bf16x4*)&ybf[(((bh * 2 + bt) * 2 + ktY) * 64 + flY) * 8 + qp] = v;
        }
        __syncthreads();  // B1: ybf ready

        f32x4 locr[2], scr[2];

        #pragma unroll
        for (int net = 0; net < 2; ++net) {
            const __bf16* w1b = w1p + (long)(net * 16 + l) * W1P_PER;
            const __bf16* w2b = w2p + (long)(net * 16 + l) * W2P_PER;
            // next G1 slot: net0 -> (net1, l); net1 -> (net0, l+1). l=15/net1
            // lands on slot 16 (net1, l0): in-bounds, values unused.
            const __bf16* w0n = w0p + (long)(net == 0 ? 16 + l : l + 1) * W0P_PER;
            const float* b0 = (net ? sb0 : lb0) + l * 256;
            const float* b1 = (net ? sb1 : lb1) + l * 256;
            const float* b2 = (net ? sb2 : lb2) + l * 64;

            bf16x8 wg2a[12];  // G2 A ring: [slot(3)][oi(4)], 48 VGPR

            // ---- G1: W0 (A, prefetched in wg1) x y^T (B, fragments) -> h0 frags
            // (r12 reuse-2: wave owns otiles {2w,2w+1}, all 4 bt)
            {
                f32x4 acc[2][4];
                #pragma unroll
                for (int oi = 0; oi < 2; ++oi)
                    #pragma unroll
                    for (int bt = 0; bt < 4; ++bt)
                        acc[oi][bt] = (f32x4){0.f, 0.f, 0.f, 0.f};
                #pragma unroll
                for (int kt = 0; kt < 2; ++kt) {
                    bf16x8 bv[4];
                    #pragma unroll
                    for (int bt = 0; bt < 4; ++bt)
                        bv[bt] = *(const bf16x8*)&ybf[((bt * 2 + kt) * 64 + lane) * 8];
                    #pragma unroll
                    for (int oi = 0; oi < 2; ++oi)
                        #pragma unroll
                        for (int bt = 0; bt < 4; ++bt)
                            acc[oi][bt] = __builtin_amdgcn_mfma_f32_16x16x32_bf16(wg1[oi * 2 + kt], bv[bt], acc[oi][bt], 0, 0, 0);
                }
                // prefetch G2 ring slots kt=0..2 (otiles {4og..4og+3}) across B2
                #pragma unroll
                for (int kt = 0; kt < 3; ++kt)
                    #pragma unroll
                    for (int oi = 0; oi < 4; ++oi)
                        wg2a[kt * 4 + oi] = ldw(w1b + (long)((4 * og + oi) * 8 + kt) * 512 + lane * 8);
                // epilogue: relu + bias -> buf1 fragments (kt1 = w)
                #pragma unroll
                for (int oi = 0; oi < 2; ++oi) {
                    f32x4 bias = *(const f32x4*)(b0 + (2 * w + oi) * 16 + quad * 4);
                    const int fl = ((oi * 2 + qh) * 16 + l16);
                    #pragma unroll
                    for (int bt = 0; bt < 4; ++bt) {
                        bf16x4 v;
                        #pragma unroll
                        for (int r = 0; r < 4; ++r)
                            v[r] = (__bf16)fmaxf(acc[oi][bt][r] + bias[r], 0.f);
                        *(bf16x4*)&buf1[((bt * 8 + w) * 64 + fl) * 8 + qp] = v;
                    }
                }
            }
            __syncthreads();  // B2: h0 ready

            bf16x8 wg3[8];    // G3 weights [kt]

            // ---- G2: W1 (A, ring-3) x h0 (B, fragments) -> h1 frags
            // REUSE-4: wave owns otiles {4og..4og+3}, batch tiles {2bh,2bh+1}.
            // bv read per-bl (4 regs live); each read feeds 4 MFMAs.
            {
                f32x4 acc[4][2];
                #pragma unroll
                for (int oi = 0; oi < 4; ++oi)
                    #pragma unroll
                    for (int bl = 0; bl < 2; ++bl)
                        acc[oi][bl] = (f32x4){0.f, 0.f, 0.f, 0.f};
                #pragma unroll
                for (int kt = 0; kt < 8; ++kt) {
                    const int slot = kt % 3;
                    #pragma unroll
                    for (int bl = 0; bl < 2; ++bl) {
                        bf16x8 bv = *(const bf16x8*)&buf1[(((2 * bh + bl) * 8 + kt) * 64 + lane) * 8];
                        #pragma unroll
                        for (int oi = 0; oi < 4; ++oi)
                            acc[oi][bl] = __builtin_amdgcn_mfma_f32_16x16x32_bf16(wg2a[slot * 4 + oi], bv, acc[oi][bl], 0, 0, 0);
                    }
                    // ring reload: slot just consumed gets kt+3 (2-iter runway)
                    if (kt < 5) {
                        #pragma unroll
                        for (int oi = 0; oi < 4; ++oi)
                            wg2a[slot * 4 + oi] = ldw(w1b + (long)((4 * og + oi) * 8 + (kt + 3)) * 512 + lane * 8);
                    }
                }
                // epilogue: relu + bias -> buf2 fragments (r16's proven mapping)
                #pragma unroll
                for (int oi = 0; oi < 4; ++oi) {
                    const int O = 4 * og + oi;
                    f32x4 bias = *(const f32x4*)(b1 + O * 16 + quad * 4);
                    const int kt1 = O >> 1;
                    const int fl  = ((O & 1) * 2 + qh) * 16 + l16;
                    #pragma unroll
                    for (int bl = 0; bl < 2; ++bl) {
                        bf16x4 v;
                        #pragma unroll
                        for (int r = 0; r < 4; ++r)
                            v[r] = (__bf16)fmaxf(acc[oi][bl][r] + bias[r], 0.f);
                        *(bf16x4*)&buf2[(((2 * bh + bl) * 8 + kt1) * 64 + fl) * 8 + qp] = v;
                    }
                }
                // prefetch G3 weights across the upcoming barrier
                #pragma unroll
                for (int kt = 0; kt < 8; ++kt)
                    wg3[kt] = ldw(w2b + (long)(og * 8 + kt) * 512 + lane * 8);
            }
            __syncthreads();  // B3: h1 ready (also all buf1 reads done)

            // ---- G3: W2 (A, prefetched in wg3) x h1 (B, fragments) -> regs
            // wave owns (dim tile og, batch half bh): bt in {2bh, 2bh+1}
            {
                f32x4 acc3[2];
                #pragma unroll
                for (int bt = 0; bt < 2; ++bt)
                    acc3[bt] = (f32x4){0.f, 0.f, 0.f, 0.f};
                #pragma unroll
                for (int kt = 0; kt < 8; ++kt) {
                    #pragma unroll
                    for (int bt = 0; bt < 2; ++bt) {
                        bf16x8 bv = *(const bf16x8*)&buf2[(((bh * 2 + bt) * 8 + kt) * 64 + lane) * 8];
                        acc3[bt] = __builtin_amdgcn_mfma_f32_16x16x32_bf16(wg3[kt], bv, acc3[bt], 0, 0, 0);
                    }
                }
                // prefetch next G1 weights (low-pressure region)
                #pragma unroll
                for (int oi = 0; oi < 2; ++oi)
                    #pragma unroll
                    for (int kt = 0; kt < 2; ++kt)
                        wg1[oi * 2 + kt] = ldw(w0n + (long)((2 * w + oi) * 2 + kt) * 512 + lane * 8);
                f32x4 bias = *(const f32x4*)(b2 + og * 16 + quad * 4);
                if (net == 0) {
                    #pragma unroll
                    for (int bt = 0; bt < 2; ++bt)
                        #pragma unroll
                        for (int r = 0; r < 4; ++r)
                            locr[bt][r] = acc3[bt][r] + bias[r];
                } else {
                    #pragma unroll
                    for (int bt = 0; bt < 2; ++bt)
                        #pragma unroll
                        for (int r = 0; r < 4; ++r)
                            scr[bt][r] = acc3[bt][r] + bias[r];
                }
            }
            // no barrier after G3: next G1 writes buf1 (reads drained at B3);
            // next G2's buf2 writes are behind the next B2
        }

        // coupling update, pure registers: y = exp(-sc) * (y - loc)
        #pragma unroll
        for (int bt = 0; bt < 2; ++bt)
            #pragma unroll
            for (int r = 0; r < 4; ++r)
                y[bt][r] = __expf(-scr[bt][r]) * (y[bt][r] - locr[bt][r]);
        // next ybf write safe: all ybf readers (both nets' G1) are behind this
        // layer's B2 barriers
    }

    #pragma unroll
    for (int bt = 0; bt < 2; ++bt)
        *(f32x4*)(out + (long)(blk * MTILE + bh * 32 + bt * 16 + l16) * DIM
                      + og * 16 + quad * 4) = y[bt];
}

extern "C" void kernel_launch(void* const* d_in, const int* in_sizes, int n_in,
                              void* d_out, int out_size, void* d_ws, size_t ws_size,
                              hipStream_t stream) {
    const float* u   = (const float*)d_in[0];
    const float* lW0 = (const float*)d_in[1];
    const float* lb0 = (const float*)d_in[2];
    const float* lW1 = (const float*)d_in[3];
    const float* lb1 = (const float*)d_in[4];
    const float* lW2 = (const float*)d_in[5];
    const float* lb2 = (const float*)d_in[6];
    const float* sW0 = (const float*)d_in[7];
    const float* sb0 = (const float*)d_in[8];
    const float* sW1 = (const float*)d_in[9];
    const float* sb1 = (const float*)d_in[10];
    const float* sW2 = (const float*)d_in[11];
    const float* sb2 = (const float*)d_in[12];
    // d_in[13..15] = M0,M1,M2 — masks are computed analytically in pack_weights

    if (ws_size < (size_t)PACK_TOT * sizeof(__bf16)) return;
    __bf16* ws = (__bf16*)d_ws;

    pack_weights<<<PACK_TOT / 8 / 256, 256, 0, stream>>>(
        lW0, lW1, lW2, sW0, sW1, sW2, ws);
    flow_kernel<<<NBLOCKS, 512, 0, stream>>>(
        u, ws, lb0, lb1, lb2, sb0, sb1, sb2, (float*)d_out);
}

// Round 11
// 302.264 us; speedup vs baseline: 3.2544x; 1.3877x over previous
//
#include <hip/hip_runtime.h>
#include <hip/hip_bf16.h>

typedef __bf16 bf16x8 __attribute__((ext_vector_type(8)));
typedef __bf16 bf16x4 __attribute__((ext_vector_type(4)));
typedef float  f32x4  __attribute__((ext_vector_type(4)));

#define LAYERS 16
#define DIM 64
#define NHID 256
#define BATCH 32768
#define MTILE 64
#define NBLOCKS (BATCH / MTILE)   // 512

// packed weight sizes in bf16 elements (r8/r12 16x16 fragment order)
#define W0P_PER 16384             // per (net,layer): 16 otiles * 2 ktiles * 512
#define W1P_PER 65536             // 16 otiles * 8 ktiles * 512
#define W2P_PER 16384             // 4 otiles * 8 ktiles * 512
#define W0P_TOT (32 * W0P_PER)    // 524288
#define W1P_TOT (32 * W1P_PER)    // 2097152
#define W2P_TOT (32 * W2P_PER)    // 524288
#define PACK_TOT (W0P_TOT + W1P_TOT + W2P_TOT)  // 3145728 bf16 = 6.29 MB

__device__ __forceinline__ bf16x8 ldw(const __bf16* p) { return *(const bf16x8*)p; }

// ---------------------------------------------------------------------------
// Pack kernel (r12, unchanged): analytic masks, 16x16 fragment order.
// ---------------------------------------------------------------------------
__global__ __launch_bounds__(256) void pack_weights(
    const float* __restrict__ lW0, const float* __restrict__ lW1, const float* __restrict__ lW2,
    const float* __restrict__ sW0, const float* __restrict__ sW1, const float* __restrict__ sW2,
    __bf16* __restrict__ ws)
{
    const long i = ((long)blockIdx.x * 256 + threadIdx.x) * 8;  // elem base
    const float* W; long src; int l, n, k, which;
    if (i < W0P_TOT) {
        int netl = (int)(i / W0P_PER), rem = (int)(i % W0P_PER);
        int net = netl >> 4; l = netl & 15;
        int nt = rem >> 10, kt = (rem >> 9) & 1, lane = (rem >> 3) & 63;
        n = nt * 16 + (lane & 15); k = kt * 32 + (lane >> 4) * 8;
        W = net ? sW0 : lW0; which = 0;
        src = (long)(l * 256 + n) * 64 + k;
    } else if (i < W0P_TOT + W1P_TOT) {
        long r = i - W0P_TOT;
        int netl = (int)(r / W1P_PER), rem = (int)(r % W1P_PER);
        int net = netl >> 4; l = netl & 15;
        int nt = rem >> 12, kt = (rem >> 9) & 7, lane = (rem >> 3) & 63;
        n = nt * 16 + (lane & 15); k = kt * 32 + (lane >> 4) * 8;
        W = net ? sW1 : lW1; which = 1;
        src = (long)(l * 256 + n) * 256 + k;
    } else {
        long r = i - W0P_TOT - W1P_TOT;
        int netl = (int)(r / W2P_PER), rem = (int)(r % W2P_PER);
        int net = netl >> 4; l = netl & 15;
        int nt = rem >> 12, kt = (rem >> 9) & 7, lane = (rem >> 3) & 63;
        n = nt * 16 + (lane & 15); k = kt * 32 + (lane >> 4) * 8;
        W = net ? sW2 : lW2; which = 2;
        src = (long)(l * 64 + n) * 256 + k;
    }
    f32x4 wa = *(const f32x4*)(W + src);
    f32x4 wb = *(const f32x4*)(W + src + 4);
    const int nm = n % 63;                   // mh(n) for which 0/1
    const int pn = (l & 1) ? 63 - n : n;     // perm(n) for which 2 (n < 64 there)
    bf16x8 o;
    #pragma unroll
    for (int j = 0; j < 8; ++j) {
        int kk = k + j;
        bool m;
        if (which == 0)      { int pk = (l & 1) ? 63 - kk : kk; m = (pk <= nm); }
        else if (which == 1) { m = ((kk % 63) <= nm); }
        else                 { m = ((kk % 63) < pn); }
        float v = (j < 4) ? wa[j] : wb[j - 4];
        o[j] = m ? (__bf16)v : (__bf16)0.0f;
    }
    *(bf16x8*)(ws + i) = o;
}

// ---------------------------------------------------------------------------
// Flow kernel, round 18: r12 champion with a REGISTER-HONEST slimming.
// r17 post-mortem: honest worst-point = acc32 + ring48 + wg3-inflight32 +
// bv8 + y8 + LOCR/SCR 16 + addr12 ~= 156 >> 128 -> reuse-4 with deep
// prefetch + 16 persistent regs can NEVER fit. Three surgical changes to
// the proven r12 structure instead:
//  1. locr/scr ELIMINATED (-16 persistent): y's only post-staging use is
//     the coupling, so fold in place: net0 G3 -> y -= (acc3+bias);
//     net1 G3 -> y *= expf(-(acc3+bias)). Algebraically identical.
//  2. G3 re-split to reuse-2: wave owns dim-pair a=w>>2 -> tiles {2a,2a+1},
//     single batch tile b3=w&3. Each buf2 read feeds 2 MFMAs -> G3 reads
//     128->64 per block-net (total 448->384, -14% on the top pipe).
//     wg3 stays 32 regs via ring-4 per dim tile (kt0..3 prefetched across
//     B3; slot reloaded with kt+4 after use; 3-iter runway, L1-warm).
//     y/ybf/out mappings re-derived for (a,b3) ownership (bijective:
//     ybf[(b3*2+a)*64 + (k*2+qh)*16+l16][qp], matches G1 reader).
//  3. G2 bv reads 2-at-a-time (-8 peak regs), same FLOPs.
// Worst point ~136 vs r12's ~150 -> spill r8-level or gone.
// G1/G2 tiling, barriers, pack: r12-identical.
// ---------------------------------------------------------------------------
__global__ void __attribute__((amdgpu_flat_work_group_size(512, 512)))
                __attribute__((amdgpu_waves_per_eu(4)))
flow_kernel(
    const float* __restrict__ u,
    const __bf16* __restrict__ wp,
    const float* __restrict__ lb0, const float* __restrict__ lb1, const float* __restrict__ lb2,
    const float* __restrict__ sb0, const float* __restrict__ sb1, const float* __restrict__ sb2,
    float* __restrict__ out)
{
    __shared__ __bf16 ybf[4 * 2 * 512];     // [bt16(4)][ktY(2)][fl(64)][8]   8 KB
    __shared__ __bf16 buf1[4 * 8 * 512];    // [bt16(4)][kt(8)][lane][8]     32 KB
    __shared__ __bf16 buf2[4 * 8 * 512];    //                               32 KB

    const int tid  = threadIdx.x;
    const int w    = tid >> 6;        // 0..7
    const int lane = tid & 63;
    const int quad = lane >> 4;
    const int l16  = lane & 15;
    const int blk  = blockIdx.x;

    const int qh = quad >> 1;
    const int qp = (quad & 1) * 4;

    const int a  = w >> 2;            // G3 dim pair: tiles {2a, 2a+1}; y dims
    const int b3 = w & 3;             // G3/y batch tile (16 rows)

    const __bf16* w0p = wp;
    const __bf16* w1p = wp + W0P_TOT;
    const __bf16* w2p = wp + W0P_TOT + W1P_TOT;

    // y regs: y[k][r] = row (blk*64 + b3*16 + l16), dim ((2a+k)*16 + quad*4 + r)
    f32x4 y[2];
    #pragma unroll
    for (int k = 0; k < 2; ++k)
        y[k] = *(const f32x4*)(u + (long)(blk * MTILE + b3 * 16 + l16) * DIM
                                 + (2 * a + k) * 16 + quad * 4);

    // prime: G1 weights for (net0, layer0) — wave's G1 otiles are {2w, 2w+1}
    bf16x8 wg1[4];   // [oi][kt]
    #pragma unroll
    for (int oi = 0; oi < 2; ++oi)
        #pragma unroll
        for (int kt = 0; kt < 2; ++kt)
            wg1[oi * 2 + kt] = ldw(w0p + (long)((2 * w + oi) * 2 + kt) * 512 + lane * 8);

    for (int l = 0; l < LAYERS; ++l) {
        // stage y -> ybf B-fragments. dim D = (2a+k)*16 + quad*4 + r:
        // ktY = D>>5 = a; k_local = k*16+quad*4+r; fl = (k_local>>3)*16+l16
        // = (k*2+qh)*16+l16; j = k_local&7 = qp+r. One bf16x4 write per k.
        #pragma unroll
        for (int k = 0; k < 2; ++k) {
            bf16x4 v;
            #pragma unroll
            for (int r = 0; r < 4; ++r) v[r] = (__bf16)y[k][r];
            *(bf16x4*)&ybf[(((b3 * 2 + a) * 64) + (k * 2 + qh) * 16 + l16) * 8 + qp] = v;
        }
        __syncthreads();  // B1: ybf ready

        #pragma unroll
        for (int net = 0; net < 2; ++net) {
            const __bf16* w1b = w1p + (long)(net * 16 + l) * W1P_PER;
            const __bf16* w2b = w2p + (long)(net * 16 + l) * W2P_PER;
            // next G1 slot: net0 -> (net1, l); net1 -> (net0, l+1). l=15/net1
            // lands on slot 16 (net1, l0): in-bounds, values unused.
            const __bf16* w0n = w0p + (long)(net == 0 ? 16 + l : l + 1) * W0P_PER;
            const float* b0 = (net ? sb0 : lb0) + l * 256;
            const float* b1 = (net ? sb1 : lb1) + l * 256;
            const float* b2 = (net ? sb2 : lb2) + l * 64;

            bf16x8 wg2a[8];  // G2 weights kt 0..3 x oi 0..1 (32 VGPR)

            // ---- G1: W0 (A, prefetched in wg1) x y^T (B, fragments) -> h0 frags
            // (r12 reuse-2: wave owns otiles {2w,2w+1}, all 4 bt)
            {
                f32x4 acc[2][4];
                #pragma unroll
                for (int oi = 0; oi < 2; ++oi)
                    #pragma unroll
                    for (int bt = 0; bt < 4; ++bt)
                        acc[oi][bt] = (f32x4){0.f, 0.f, 0.f, 0.f};
                #pragma unroll
                for (int kt = 0; kt < 2; ++kt) {
                    bf16x8 bv[4];
                    #pragma unroll
                    for (int bt = 0; bt < 4; ++bt)
                        bv[bt] = *(const bf16x8*)&ybf[((bt * 2 + kt) * 64 + lane) * 8];
                    #pragma unroll
                    for (int oi = 0; oi < 2; ++oi)
                        #pragma unroll
                        for (int bt = 0; bt < 4; ++bt)
                            acc[oi][bt] = __builtin_amdgcn_mfma_f32_16x16x32_bf16(wg1[oi * 2 + kt], bv[bt], acc[oi][bt], 0, 0, 0);
                }
                // prefetch G2 kt=0..3 across the upcoming barrier
                #pragma unroll
                for (int kt = 0; kt < 4; ++kt)
                    #pragma unroll
                    for (int oi = 0; oi < 2; ++oi)
                        wg2a[kt * 2 + oi] = ldw(w1b + (long)((2 * w + oi) * 8 + kt) * 512 + lane * 8);
                // epilogue: relu + bias -> buf1 fragments (kt1 = w)
                #pragma unroll
                for (int oi = 0; oi < 2; ++oi) {
                    f32x4 bias = *(const f32x4*)(b0 + (2 * w + oi) * 16 + quad * 4);
                    const int fl = ((oi * 2 + qh) * 16 + l16);
                    #pragma unroll
                    for (int bt = 0; bt < 4; ++bt) {
                        bf16x4 v;
                        #pragma unroll
                        for (int r = 0; r < 4; ++r)
                            v[r] = (__bf16)fmaxf(acc[oi][bt][r] + bias[r], 0.f);
                        *(bf16x4*)&buf1[((bt * 8 + w) * 64 + fl) * 8 + qp] = v;
                    }
                }
            }
            __syncthreads();  // B2: h0 ready

            bf16x8 wg3[8];    // G3 A ring: [k(2)][slot(4)], 32 VGPR

            // ---- G2: W1 (A, kt<4 prefetched) x h0 (B, fragments) -> h1 frags
            // r12 reuse-2; bv read 2-at-a-time to trim peak regs.
            {
                f32x4 acc[2][4];
                #pragma unroll
                for (int oi = 0; oi < 2; ++oi)
                    #pragma unroll
                    for (int bt = 0; bt < 4; ++bt)
                        acc[oi][bt] = (f32x4){0.f, 0.f, 0.f, 0.f};
                #pragma unroll
                for (int kt = 0; kt < 8; ++kt) {
                    bf16x8 aw[2];
                    #pragma unroll
                    for (int oi = 0; oi < 2; ++oi)
                        aw[oi] = (kt < 4) ? wg2a[kt * 2 + oi]
                                          : ldw(w1b + (long)((2 * w + oi) * 8 + kt) * 512 + lane * 8);
                    #pragma unroll
                    for (int h = 0; h < 2; ++h) {
                        bf16x8 bv[2];
                        #pragma unroll
                        for (int bl = 0; bl < 2; ++bl)
                            bv[bl] = *(const bf16x8*)&buf1[(((2 * h + bl) * 8 + kt) * 64 + lane) * 8];
                        #pragma unroll
                        for (int oi = 0; oi < 2; ++oi)
                            #pragma unroll
                            for (int bl = 0; bl < 2; ++bl)
                                acc[oi][2 * h + bl] = __builtin_amdgcn_mfma_f32_16x16x32_bf16(aw[oi], bv[bl], acc[oi][2 * h + bl], 0, 0, 0);
                    }
                }
                // epilogue: relu + bias -> buf2 fragments
                #pragma unroll
                for (int oi = 0; oi < 2; ++oi) {
                    f32x4 bias = *(const f32x4*)(b1 + (2 * w + oi) * 16 + quad * 4);
                    const int fl = ((oi * 2 + qh) * 16 + l16);
                    #pragma unroll
                    for (int bt = 0; bt < 4; ++bt) {
                        bf16x4 v;
                        #pragma unroll
                        for (int r = 0; r < 4; ++r)
                            v[r] = (__bf16)fmaxf(acc[oi][bt][r] + bias[r], 0.f);
                        *(bf16x4*)&buf2[((bt * 8 + w) * 64 + fl) * 8 + qp] = v;
                    }
                }
                // prefetch G3 ring slots kt=0..3 for dim tiles {2a, 2a+1}
                // across the upcoming barrier (4 waves share each tile: L1-warm)
                #pragma unroll
                for (int k = 0; k < 2; ++k)
                    #pragma unroll
                    for (int s = 0; s < 4; ++s)
                        wg3[k * 4 + s] = ldw(w2b + (long)((2 * a + k) * 8 + s) * 512 + lane * 8);
            }
            __syncthreads();  // B3: h1 ready (also all buf1 reads done)

            // ---- G3: W2 (A, ring-4 in wg3) x h1 (B, fragments) -> y update
            // REUSE-2: wave owns dim tiles {2a, 2a+1}, batch tile b3.
            // One bv read per kt feeds 2 MFMAs. Ring: slot kt reloaded with
            // kt+4 after use (3-iter runway).
            {
                f32x4 acc3[2];
                #pragma unroll
                for (int k = 0; k < 2; ++k)
                    acc3[k] = (f32x4){0.f, 0.f, 0.f, 0.f};
                #pragma unroll
                for (int kt = 0; kt < 8; ++kt) {
                    bf16x8 bv = *(const bf16x8*)&buf2[((b3 * 8 + kt) * 64 + lane) * 8];
                    #pragma unroll
                    for (int k = 0; k < 2; ++k)
                        acc3[k] = __builtin_amdgcn_mfma_f32_16x16x32_bf16(wg3[k * 4 + (kt & 3)], bv, acc3[k], 0, 0, 0);
                    if (kt < 4) {
                        #pragma unroll
                        for (int k = 0; k < 2; ++k)
                            wg3[k * 4 + kt] = ldw(w2b + (long)((2 * a + k) * 8 + (kt + 4)) * 512 + lane * 8);
                    }
                }
                // prefetch next G1 weights (low-pressure region)
                #pragma unroll
                for (int oi = 0; oi < 2; ++oi)
                    #pragma unroll
                    for (int kt = 0; kt < 2; ++kt)
                        wg1[oi * 2 + kt] = ldw(w0n + (long)((2 * w + oi) * 2 + kt) * 512 + lane * 8);
                // coupling folded in place: no locr/scr registers.
                // C-frag: col = lane&15 = batch row (matches y), row = quad*4+r.
                if (net == 0) {
                    #pragma unroll
                    for (int k = 0; k < 2; ++k) {
                        f32x4 bias = *(const f32x4*)(b2 + (2 * a + k) * 16 + quad * 4);
                        #pragma unroll
                        for (int r = 0; r < 4; ++r)
                            y[k][r] -= (acc3[k][r] + bias[r]);   // y = y - loc
                    }
                } else {
                    #pragma unroll
                    for (int k = 0; k < 2; ++k) {
                        f32x4 bias = *(const f32x4*)(b2 + (2 * a + k) * 16 + quad * 4);
                        #pragma unroll
                        for (int r = 0; r < 4; ++r)
                            y[k][r] = __expf(-(acc3[k][r] + bias[r])) * y[k][r];
                    }
                }
            }
            // no barrier after G3: next G1 writes buf1 (reads drained at B3);
            // next G2's buf2 writes are behind the next B2
        }
        // next ybf write safe: all ybf readers (both nets' G1) are behind this
        // layer's B2 barriers
    }

    #pragma unroll
    for (int k = 0; k < 2; ++k)
        *(f32x4*)(out + (long)(blk * MTILE + b3 * 16 + l16) * DIM
                      + (2 * a + k) * 16 + quad * 4) = y[k];
}

extern "C" void kernel_launch(void* const* d_in, const int* in_sizes, int n_in,
                              void* d_out, int out_size, void* d_ws, size_t ws_size,
                              hipStream_t stream) {
    const float* u   = (const float*)d_in[0];
    const float* lW0 = (const float*)d_in[1];
    const float* lb0 = (const float*)d_in[2];
    const float* lW1 = (const float*)d_in[3];
    const float* lb1 = (const float*)d_in[4];
    const float* lW2 = (const float*)d_in[5];
    const float* lb2 = (const float*)d_in[6];
    const float* sW0 = (const float*)d_in[7];
    const float* sb0 = (const float*)d_in[8];
    const float* sW1 = (const float*)d_in[9];
    const float* sb1 = (const float*)d_in[10];
    const float* sW2 = (const float*)d_in[11];
    const float* sb2 = (const float*)d_in[12];
    // d_in[13..15] = M0,M1,M2 — masks are computed analytically in pack_weights

    if (ws_size < (size_t)PACK_TOT * sizeof(__bf16)) return;
    __bf16* ws = (__bf16*)d_ws;

    pack_weights<<<PACK_TOT / 8 / 256, 256, 0, stream>>>(
        lW0, lW1, lW2, sW0, sW1, sW2, ws);
    flow_kernel<<<NBLOCKS, 512, 0, stream>>>(
        u, ws, lb0, lb1, lb2, sb0, sb1, sb2, (float*)d_out);
}

// Round 12
// 299.354 us; speedup vs baseline: 3.2861x; 1.0097x over previous
//
#include <hip/hip_runtime.h>
#include <hip/hip_bf16.h>

typedef __bf16 bf16x8 __attribute__((ext_vector_type(8)));
typedef __bf16 bf16x4 __attribute__((ext_vector_type(4)));
typedef float  f32x4  __attribute__((ext_vector_type(4)));

#define LAYERS 16
#define DIM 64
#define NHID 256
#define BATCH 32768
#define MTILE 64
#define NBLOCKS (BATCH / MTILE)   // 512

// packed weight sizes in bf16 elements (r8/r12 16x16 fragment order)
#define W0P_PER 16384             // per (net,layer): 16 otiles * 2 ktiles * 512
#define W1P_PER 65536             // 16 otiles * 8 ktiles * 512
#define W2P_PER 16384             // 4 otiles * 8 ktiles * 512
#define W0P_TOT (32 * W0P_PER)    // 524288
#define W1P_TOT (32 * W1P_PER)    // 2097152
#define W2P_TOT (32 * W2P_PER)    // 524288
#define PACK_TOT (W0P_TOT + W1P_TOT + W2P_TOT)  // 3145728 bf16 = 6.29 MB

__device__ __forceinline__ bf16x8 ldw(const __bf16* p) { return *(const bf16x8*)p; }

// Barrier with LDS-only drain: all inter-phase traffic in this kernel is
// ds_write -> ds_read (no global->LDS, global stores only at kernel end),
// so only lgkmcnt must drain before the rendezvous. __syncthreads() would
// also force s_waitcnt vmcnt(0), draining the weight prefetches issued in
// the current phase — the documented barrier-drain stall (m97 ceiling).
// Raw s_barrier + counted wait keeps those loads in flight across the
// barrier. "memory"-clobbered asm on both sides pins memory-op ordering.
__device__ __forceinline__ void lds_barrier() {
    asm volatile("s_waitcnt lgkmcnt(0)" ::: "memory");
    __builtin_amdgcn_s_barrier();
    asm volatile("" ::: "memory");
}

// ---------------------------------------------------------------------------
// Pack kernel (r12, unchanged): analytic masks, 16x16 fragment order.
// ---------------------------------------------------------------------------
__global__ __launch_bounds__(256) void pack_weights(
    const float* __restrict__ lW0, const float* __restrict__ lW1, const float* __restrict__ lW2,
    const float* __restrict__ sW0, const float* __restrict__ sW1, const float* __restrict__ sW2,
    __bf16* __restrict__ ws)
{
    const long i = ((long)blockIdx.x * 256 + threadIdx.x) * 8;  // elem base
    const float* W; long src; int l, n, k, which;
    if (i < W0P_TOT) {
        int netl = (int)(i / W0P_PER), rem = (int)(i % W0P_PER);
        int net = netl >> 4; l = netl & 15;
        int nt = rem >> 10, kt = (rem >> 9) & 1, lane = (rem >> 3) & 63;
        n = nt * 16 + (lane & 15); k = kt * 32 + (lane >> 4) * 8;
        W = net ? sW0 : lW0; which = 0;
        src = (long)(l * 256 + n) * 64 + k;
    } else if (i < W0P_TOT + W1P_TOT) {
        long r = i - W0P_TOT;
        int netl = (int)(r / W1P_PER), rem = (int)(r % W1P_PER);
        int net = netl >> 4; l = netl & 15;
        int nt = rem >> 12, kt = (rem >> 9) & 7, lane = (rem >> 3) & 63;
        n = nt * 16 + (lane & 15); k = kt * 32 + (lane >> 4) * 8;
        W = net ? sW1 : lW1; which = 1;
        src = (long)(l * 256 + n) * 256 + k;
    } else {
        long r = i - W0P_TOT - W1P_TOT;
        int netl = (int)(r / W2P_PER), rem = (int)(r % W2P_PER);
        int net = netl >> 4; l = netl & 15;
        int nt = rem >> 12, kt = (rem >> 9) & 7, lane = (rem >> 3) & 63;
        n = nt * 16 + (lane & 15); k = kt * 32 + (lane >> 4) * 8;
        W = net ? sW2 : lW2; which = 2;
        src = (long)(l * 64 + n) * 256 + k;
    }
    f32x4 wa = *(const f32x4*)(W + src);
    f32x4 wb = *(const f32x4*)(W + src + 4);
    const int nm = n % 63;                   // mh(n) for which 0/1
    const int pn = (l & 1) ? 63 - n : n;     // perm(n) for which 2 (n < 64 there)
    bf16x8 o;
    #pragma unroll
    for (int j = 0; j < 8; ++j) {
        int kk = k + j;
        bool m;
        if (which == 0)      { int pk = (l & 1) ? 63 - kk : kk; m = (pk <= nm); }
        else if (which == 1) { m = ((kk % 63) <= nm); }
        else                 { m = ((kk % 63) < pn); }
        float v = (j < 4) ? wa[j] : wb[j - 4];
        o[j] = m ? (__bf16)v : (__bf16)0.0f;
    }
    *(bf16x8*)(ws + i) = o;
}

// ---------------------------------------------------------------------------
// Flow kernel, round 19: the r12 champion structure (234us; G1/G2 reuse-2
// with deep prefetch, G3 per-(otD,bh), proven mappings) + two orthogonal,
// individually-safe changes:
//  1. COUPLING FOLDED INTO y (r18-proven): net0 G3 -> y -= (acc3+bias);
//     net1 G3 -> y *= expf(-(acc3+bias)). Eliminates locr/scr (-16
//     persistent regs) -> r12's ~16-reg mild spill should vanish
//     (WRITE 17.4 -> ~8.2 MB).
//  2. COUNTED-WAIT BARRIERS: lds_barrier() = s_waitcnt lgkmcnt(0) +
//     raw s_barrier, replacing __syncthreads' vmcnt(0)+lgkmcnt(0) drain.
//     Weight prefetches (wg2a across B2, wg3 across B3, wg1 across the
//     layer tail) now genuinely stay in flight across barriers instead of
//     being force-drained at each one (the m97-style ~20% barrier stall).
// Everything else byte-identical to r12.
// ---------------------------------------------------------------------------
__global__ void __attribute__((amdgpu_flat_work_group_size(512, 512)))
                __attribute__((amdgpu_waves_per_eu(4)))
flow_kernel(
    const float* __restrict__ u,
    const __bf16* __restrict__ wp,
    const float* __restrict__ lb0, const float* __restrict__ lb1, const float* __restrict__ lb2,
    const float* __restrict__ sb0, const float* __restrict__ sb1, const float* __restrict__ sb2,
    float* __restrict__ out)
{
    __shared__ __bf16 ybf[4 * 2 * 512];     // [bt][kt(2)][lane][8]   8 KB
    __shared__ __bf16 buf1[4 * 8 * 512];    // [bt][kt(8)][lane][8]  32 KB
    __shared__ __bf16 buf2[4 * 8 * 512];    //                       32 KB

    const int tid  = threadIdx.x;
    const int w    = tid >> 6;        // 0..7
    const int lane = tid & 63;
    const int quad = lane >> 4;
    const int l16  = lane & 15;
    const int blk  = blockIdx.x;

    const int qh = quad >> 1;
    const int qp = (quad & 1) * 4;

    const int otD = w >> 1;           // G3 dim tile (0..3); y dim slice
    const int bh  = w & 1;            // G3 batch half; y batch half

    const __bf16* w0p = wp;
    const __bf16* w1p = wp + W0P_TOT;
    const __bf16* w2p = wp + W0P_TOT + W1P_TOT;

    // y regs: y[bt][r] = row (blk*64 + bh*32 + bt*16 + l16), dim (otD*16 + quad*4 + r)
    f32x4 y[2];
    #pragma unroll
    for (int bt = 0; bt < 2; ++bt)
        y[bt] = *(const f32x4*)(u + (long)(blk * MTILE + bh * 32 + bt * 16 + l16) * DIM
                                  + otD * 16 + quad * 4);

    // y-staging fragment coords: ktY = w>>2, flY as in r12
    const int ktY = w >> 2;
    const int flY = ((((w >> 1) & 1) * 2 + qh) * 16 + l16);

    // prime: G1 weights for (net0, layer0) — wave's otiles are {2w, 2w+1}
    bf16x8 wg1[4];   // [oi][kt]
    #pragma unroll
    for (int oi = 0; oi < 2; ++oi)
        #pragma unroll
        for (int kt = 0; kt < 2; ++kt)
            wg1[oi * 2 + kt] = ldw(w0p + (long)((2 * w + oi) * 2 + kt) * 512 + lane * 8);

    for (int l = 0; l < LAYERS; ++l) {
        // stage y -> bf16 B-fragments (one b64 write per bt)
        #pragma unroll
        for (int bt = 0; bt < 2; ++bt) {
            bf16x4 v;
            #pragma unroll
            for (int r = 0; r < 4; ++r) v[r] = (__bf16)y[bt][r];
            *(bf16x4*)&ybf[(((bh * 2 + bt) * 2 + ktY) * 64 + flY) * 8 + qp] = v;
        }
        lds_barrier();  // B1: ybf ready

        #pragma unroll
        for (int net = 0; net < 2; ++net) {
            const __bf16* w1b = w1p + (long)(net * 16 + l) * W1P_PER;
            const __bf16* w2b = w2p + (long)(net * 16 + l) * W2P_PER;
            // next G1 slot: net0 -> (net1, l); net1 -> (net0, l+1). l=15/net1
            // lands on slot 16 (net1, l0): in-bounds, values unused.
            const __bf16* w0n = w0p + (long)(net == 0 ? 16 + l : l + 1) * W0P_PER;
            const float* b0 = (net ? sb0 : lb0) + l * 256;
            const float* b1 = (net ? sb1 : lb1) + l * 256;
            const float* b2 = (net ? sb2 : lb2) + l * 64;

            bf16x8 wg2a[8];  // G2 weights kt 0..3 x oi 0..1

            // ---- G1: W0 (A, prefetched in wg1) x y^T (B, fragments) -> h0 frags
            {
                f32x4 acc[2][4];
                #pragma unroll
                for (int oi = 0; oi < 2; ++oi)
                    #pragma unroll
                    for (int bt = 0; bt < 4; ++bt)
                        acc[oi][bt] = (f32x4){0.f, 0.f, 0.f, 0.f};
                #pragma unroll
                for (int kt = 0; kt < 2; ++kt) {
                    bf16x8 bv[4];
                    #pragma unroll
                    for (int bt = 0; bt < 4; ++bt)
                        bv[bt] = *(const bf16x8*)&ybf[((bt * 2 + kt) * 64 + lane) * 8];
                    #pragma unroll
                    for (int oi = 0; oi < 2; ++oi)
                        #pragma unroll
                        for (int bt = 0; bt < 4; ++bt)
                            acc[oi][bt] = __builtin_amdgcn_mfma_f32_16x16x32_bf16(wg1[oi * 2 + kt], bv[bt], acc[oi][bt], 0, 0, 0);
                }
                // prefetch G2 kt=0..3 across the upcoming barrier (stays in
                // flight: lds_barrier does not drain vmcnt)
                #pragma unroll
                for (int kt = 0; kt < 4; ++kt)
                    #pragma unroll
                    for (int oi = 0; oi < 2; ++oi)
                        wg2a[kt * 2 + oi] = ldw(w1b + (long)((2 * w + oi) * 8 + kt) * 512 + lane * 8);
                // epilogue: relu + bias -> buf1 fragments (kt1 = w)
                #pragma unroll
                for (int oi = 0; oi < 2; ++oi) {
                    f32x4 bias = *(const f32x4*)(b0 + (2 * w + oi) * 16 + quad * 4);
                    const int fl = ((oi * 2 + qh) * 16 + l16);
                    #pragma unroll
                    for (int bt = 0; bt < 4; ++bt) {
                        bf16x4 v;
                        #pragma unroll
                        for (int r = 0; r < 4; ++r)
                            v[r] = (__bf16)fmaxf(acc[oi][bt][r] + bias[r], 0.f);
                        *(bf16x4*)&buf1[((bt * 8 + w) * 64 + fl) * 8 + qp] = v;
                    }
                }
            }
            lds_barrier();  // B2: h0 ready

            bf16x8 wg3[8];    // G3 weights [kt]

            // ---- G2: W1 (A, kt<4 prefetched) x h0 (B, fragments) -> h1 frags
            {
                f32x4 acc[2][4];
                #pragma unroll
                for (int oi = 0; oi < 2; ++oi)
                    #pragma unroll
                    for (int bt = 0; bt < 4; ++bt)
                        acc[oi][bt] = (f32x4){0.f, 0.f, 0.f, 0.f};
                #pragma unroll
                for (int kt = 0; kt < 8; ++kt) {
                    bf16x8 aw[2];
                    #pragma unroll
                    for (int oi = 0; oi < 2; ++oi)
                        aw[oi] = (kt < 4) ? wg2a[kt * 2 + oi]
                                          : ldw(w1b + (long)((2 * w + oi) * 8 + kt) * 512 + lane * 8);
                    bf16x8 bv[4];
                    #pragma unroll
                    for (int bt = 0; bt < 4; ++bt)
                        bv[bt] = *(const bf16x8*)&buf1[((bt * 8 + kt) * 64 + lane) * 8];
                    #pragma unroll
                    for (int oi = 0; oi < 2; ++oi)
                        #pragma unroll
                        for (int bt = 0; bt < 4; ++bt)
                            acc[oi][bt] = __builtin_amdgcn_mfma_f32_16x16x32_bf16(aw[oi], bv[bt], acc[oi][bt], 0, 0, 0);
                }
                // epilogue: relu + bias -> buf2 fragments
                #pragma unroll
                for (int oi = 0; oi < 2; ++oi) {
                    f32x4 bias = *(const f32x4*)(b1 + (2 * w + oi) * 16 + quad * 4);
                    const int fl = ((oi * 2 + qh) * 16 + l16);
                    #pragma unroll
                    for (int bt = 0; bt < 4; ++bt) {
                        bf16x4 v;
                        #pragma unroll
                        for (int r = 0; r < 4; ++r)
                            v[r] = (__bf16)fmaxf(acc[oi][bt][r] + bias[r], 0.f);
                        *(bf16x4*)&buf2[((bt * 8 + w) * 64 + fl) * 8 + qp] = v;
                    }
                }
                // prefetch G3 weights across the upcoming barrier (wave pair
                // w, w^1 load the same otD tile — L2/L1-served, negligible)
                #pragma unroll
                for (int kt = 0; kt < 8; ++kt)
                    wg3[kt] = ldw(w2b + (long)(otD * 8 + kt) * 512 + lane * 8);
            }
            lds_barrier();  // B3: h1 ready (also all buf1 reads done)

            // ---- G3: W2 (A, prefetched in wg3) x h1 (B, fragments) -> y update
            // wave owns (dim tile otD, batch half bh): bt in {2bh, 2bh+1}.
            // C-frag: col = lane&15 = batch row (matches y), row = quad*4+r.
            {
                f32x4 acc3[2];
                #pragma unroll
                for (int bt = 0; bt < 2; ++bt)
                    acc3[bt] = (f32x4){0.f, 0.f, 0.f, 0.f};
                #pragma unroll
                for (int kt = 0; kt < 8; ++kt) {
                    #pragma unroll
                    for (int bt = 0; bt < 2; ++bt) {
                        bf16x8 bv = *(const bf16x8*)&buf2[(((bh * 2 + bt) * 8 + kt) * 64 + lane) * 8];
                        acc3[bt] = __builtin_amdgcn_mfma_f32_16x16x32_bf16(wg3[kt], bv, acc3[bt], 0, 0, 0);
                    }
                }
                // prefetch next G1 weights (low-pressure region)
                #pragma unroll
                for (int oi = 0; oi < 2; ++oi)
                    #pragma unroll
                    for (int kt = 0; kt < 2; ++kt)
                        wg1[oi * 2 + kt] = ldw(w0n + (long)((2 * w + oi) * 2 + kt) * 512 + lane * 8);
                // coupling folded in place: no locr/scr registers.
                f32x4 bias = *(const f32x4*)(b2 + otD * 16 + quad * 4);
                if (net == 0) {
                    #pragma unroll
                    for (int bt = 0; bt < 2; ++bt)
                        #pragma unroll
                        for (int r = 0; r < 4; ++r)
                            y[bt][r] -= (acc3[bt][r] + bias[r]);   // y = y - loc
                } else {
                    #pragma unroll
                    for (int bt = 0; bt < 2; ++bt)
                        #pragma unroll
                        for (int r = 0; r < 4; ++r)
                            y[bt][r] = __expf(-(acc3[bt][r] + bias[r])) * y[bt][r];
                }
            }
            // no barrier after G3: next G1 writes buf1 (reads drained at B3);
            // next G2's buf2 writes are behind the next B2
        }
        // next ybf write safe: all ybf readers (both nets' G1) are behind this
        // layer's B2 barriers
    }

    #pragma unroll
    for (int bt = 0; bt < 2; ++bt)
        *(f32x4*)(out + (long)(blk * MTILE + bh * 32 + bt * 16 + l16) * DIM
                      + otD * 16 + quad * 4) = y[bt];
}

extern "C" void kernel_launch(void* const* d_in, const int* in_sizes, int n_in,
                              void* d_out, int out_size, void* d_ws, size_t ws_size,
                              hipStream_t stream) {
    const float* u   = (const float*)d_in[0];
    const float* lW0 = (const float*)d_in[1];
    const float* lb0 = (const float*)d_in[2];
    const float* lW1 = (const float*)d_in[3];
    const float* lb1 = (const float*)d_in[4];
    const float* lW2 = (const float*)d_in[5];
    const float* lb2 = (const float*)d_in[6];
    const float* sW0 = (const float*)d_in[7];
    const float* sb0 = (const float*)d_in[8];
    const float* sW1 = (const float*)d_in[9];
    const float* sb1 = (const float*)d_in[10];
    const float* sW2 = (const float*)d_in[11];
    const float* sb2 = (const float*)d_in[12];
    // d_in[13..15] = M0,M1,M2 — masks are computed analytically in pack_weights

    if (ws_size < (size_t)PACK_TOT * sizeof(__bf16)) return;
    __bf16* ws = (__bf16*)d_ws;

    pack_weights<<<PACK_TOT / 8 / 256, 256, 0, stream>>>(
        lW0, lW1, lW2, sW0, sW1, sW2, ws);
    flow_kernel<<<NBLOCKS, 512, 0, stream>>>(
        u, ws, lb0, lb1, lb2, sb0, sb1, sb2, (float*)d_out);
}